// Round 9
// baseline (541.938 us; speedup 1.0000x reference)
//
#include <hip/hip_runtime.h>

typedef __attribute__((ext_vector_type(8))) short bf16x8;
typedef __attribute__((ext_vector_type(4))) float f32x4;
typedef __attribute__((ext_vector_type(4))) unsigned short us4;
typedef __attribute__((ext_vector_type(8))) unsigned short us8;

static __device__ __forceinline__ float bf2f(unsigned short u) {
    union { unsigned int i; float f; } cv; cv.i = ((unsigned int)u) << 16;
    return cv.f;
}
static __device__ __forceinline__ unsigned short f2bf(float f) {
    union { float f; unsigned int i; } cv; cv.f = f;
    unsigned int x = cv.i;
    unsigned int lsb = (x >> 16) & 1u;
    x += 0x7fffu + lsb;
    return (unsigned short)(x >> 16);
}

// async global->LDS, 16B per lane; LDS dest is wave-uniform base + lane*16
static __device__ __forceinline__ void gload16(const void* g, void* l) {
    __builtin_amdgcn_global_load_lds(
        (const __attribute__((address_space(1))) void*)g,
        (__attribute__((address_space(3))) void*)l, 16, 0, 0);
}

// ---------------- zero (hipMemsetAsync's runtime fill kernel is pathological) ----
__global__ __launch_bounds__(256) void k_zero(int* __restrict__ p, int n) {
    int i = blockIdx.x * 256 + threadIdx.x;
    if (i < n) p[i] = 0;
}

// ---------------- CSR build ----------------
__global__ __launch_bounds__(256) void k_hist(const int* __restrict__ dst,
                                              int* __restrict__ cnt, int E) {
    int i = blockIdx.x * 256 + threadIdx.x;
    if (i < E) atomicAdd(&cnt[dst[i]], 1);
}

__global__ __launch_bounds__(256) void k_bsum(const int* __restrict__ cnt,
                                              int* __restrict__ bsum, int M) {
    __shared__ int sm[256];
    int t = threadIdx.x;
    int base = blockIdx.x * 1024 + t * 4;
    int s = 0;
#pragma unroll
    for (int j = 0; j < 4; ++j) {
        int i = base + j;
        if (i < M) s += cnt[i];
    }
    sm[t] = s;
    __syncthreads();
    for (int off = 128; off; off >>= 1) {
        if (t < off) sm[t] += sm[t + off];
        __syncthreads();
    }
    if (t == 0) bsum[blockIdx.x] = sm[0];
}

__global__ void k_scanb(int* __restrict__ bsum, int NB,
                        int* __restrict__ rowptr, int M, int E) {
    if (threadIdx.x == 0 && blockIdx.x == 0) {
        int run = 0;
        for (int b = 0; b < NB; ++b) {
            int v = bsum[b];
            bsum[b] = run;
            run += v;
        }
        rowptr[M] = E;
    }
}

__global__ __launch_bounds__(256) void k_rowptr(const int* __restrict__ cnt,
                                                const int* __restrict__ bsum,
                                                int* __restrict__ rowptr,
                                                int* __restrict__ cursor, int M) {
    __shared__ int sm[256];
    int t = threadIdx.x;
    int base = blockIdx.x * 1024 + t * 4;
    int c[4];
    int ts = 0;
#pragma unroll
    for (int j = 0; j < 4; ++j) {
        int i = base + j;
        c[j] = (i < M) ? cnt[i] : 0;
        ts += c[j];
    }
    sm[t] = ts;
    __syncthreads();
    for (int off = 1; off < 256; off <<= 1) {
        int v = (t >= off) ? sm[t - off] : 0;
        __syncthreads();
        sm[t] += v;
        __syncthreads();
    }
    int ex = bsum[blockIdx.x] + sm[t] - ts;
#pragma unroll
    for (int j = 0; j < 4; ++j) {
        int i = base + j;
        if (i < M) {
            rowptr[i] = ex;
            cursor[i] = ex;
        }
        ex += c[j];
    }
}

__global__ __launch_bounds__(256) void k_place(const int* __restrict__ src,
                                               const int* __restrict__ dst,
                                               int* __restrict__ cursor,
                                               int* __restrict__ eidx, int E) {
    int i = blockIdx.x * 256 + threadIdx.x;
    if (i < E) {
        int slot = atomicAdd(&cursor[dst[i]], 1);
        eidx[slot] = src[i];
    }
}

// ---------------- f32 -> bf16 row-major convert ----------------
__global__ __launch_bounds__(256) void k_convx(const float* __restrict__ x,
                                               unsigned short* __restrict__ xb, int n8) {
    int i = blockIdx.x * 256 + threadIdx.x;
    if (i >= n8) return;
    const f32x4* p = (const f32x4*)(x + (size_t)i * 8);
    f32x4 u0 = p[0], u1 = p[1];
    union { us8 v; unsigned short u[8]; } tmp;
    tmp.u[0] = f2bf(u0.x); tmp.u[1] = f2bf(u0.y);
    tmp.u[2] = f2bf(u0.z); tmp.u[3] = f2bf(u0.w);
    tmp.u[4] = f2bf(u1.x); tmp.u[5] = f2bf(u1.y);
    tmp.u[6] = f2bf(u1.z); tmp.u[7] = f2bf(u1.w);
    *(us8*)(xb + (size_t)i * 8) = tmp.v;
}

// ---------------- weight conversion into K-tiled fragment order ----------------
__global__ __launch_bounds__(256) void k_convw(const float* __restrict__ Wl,
                                               const float* __restrict__ Wr,
                                               const float* __restrict__ fcW,
                                               unsigned short* __restrict__ Wc1,
                                               unsigned short* __restrict__ Wc2,
                                               unsigned short* __restrict__ fcWb) {
    int idx = blockIdx.x * 256 + threadIdx.x;
    if (idx < 262144) {
        int layer = idx >> 17;
        int i = idx & 131071;
        int kt = i >> 14;
        int sub = (i >> 10) & 15;
        int kk = (i >> 9) & 1;
        int sl = (i >> 3) & 63;
        int e = i & 7;
        int n = sub * 16 + (sl & 15);
        int k = kt * 64 + kk * 32 + (sl >> 4) * 8 + e;
        int base = layer * 196608;
        float v = (k < 256) ? Wl[base + n * 256 + k] : Wr[base + n * 256 + (k - 256)];
        (layer ? Wc2 : Wc1)[i] = f2bf(v);
    } else {
        int i = idx - 262144;
        if (i < 32768) {
            int kt = i >> 13;
            int sub = (i >> 10) & 7;
            int kk = (i >> 9) & 1;
            int sl = (i >> 3) & 63;
            int e = i & 7;
            int n = sub * 16 + (sl & 15);
            int k = kt * 64 + kk * 32 + (sl >> 4) * 8 + e;
            fcWb[i] = f2bf(fcW[n * 256 + k]);
        }
    }
}

// gather 16 rows per wave into the mean LDS tile (fragment-major).
// lane l covers k-slice [l*4, l*4+4); Msm addr derived so that the GEMM's
// af read (Msm[kt*4096 + n*1024 + kk*512 + l*8]) sees row n*16+(l&15), k kt*64+kk*32+(l>>4)*8.
#define GATHER_MEAN(Msm_, xsg_)                                                          \
  {                                                                                      \
    const int maddr = (l >> 4) * 4096 + w * 1024 + ((l & 15) >> 3) * 512 + (l & 1) * 4   \
                    + (((l >> 1) & 3) * 16) * 8;                                         \
    for (int i = 0; i < 16; ++i) {                                                       \
      int r = row0 + w * 16 + i;                                                         \
      float a0 = 0.f, a1 = 0.f, a2 = 0.f, a3 = 0.f;                                      \
      int s0 = 0, s1 = 0;                                                                \
      if (r < M) { s0 = rowptr[r]; s1 = rowptr[r + 1]; }                                 \
      int e = s0;                                                                        \
      for (; e + 2 <= s1; e += 2) {                                                      \
        int sA = eidx[e], sB = eidx[e + 1];                                              \
        us4 vA = *((const us4*)(xsg_ + (size_t)sA * 256) + l);                           \
        us4 vB = *((const us4*)(xsg_ + (size_t)sB * 256) + l);                           \
        a0 += bf2f(vA.x) + bf2f(vB.x);                                                   \
        a1 += bf2f(vA.y) + bf2f(vB.y);                                                   \
        a2 += bf2f(vA.z) + bf2f(vB.z);                                                   \
        a3 += bf2f(vA.w) + bf2f(vB.w);                                                   \
      }                                                                                  \
      if (e < s1) {                                                                      \
        int sA = eidx[e];                                                                \
        us4 vA = *((const us4*)(xsg_ + (size_t)sA * 256) + l);                           \
        a0 += bf2f(vA.x); a1 += bf2f(vA.y); a2 += bf2f(vA.z); a3 += bf2f(vA.w);          \
      }                                                                                  \
      float rinv = (s1 > s0) ? 1.0f / (float)(s1 - s0) : 0.0f;                           \
      us4 o;                                                                             \
      o.x = f2bf(a0 * rinv); o.y = f2bf(a1 * rinv);                                      \
      o.z = f2bf(a2 * rinv); o.w = f2bf(a3 * rinv);                                      \
      *(us4*)(&Msm_[maddr + i * 8]) = o;                                                 \
    }                                                                                    \
  }

// ---------------- FUSED gather + layer-1 GEMM: h = relu([mean | xs] @ Wc^T + bias) ----
// BM=64, BN=256(full), K=512. Mean half (kt0-3) computed in-kernel into LDS (no HBM
// round-trip); xs half (kt4-7) staged up-front via 8 gload_lds hidden under kt0-3 MFMA.
__global__ __launch_bounds__(256, 2) void k_sage_g1(const unsigned short* __restrict__ xs,
                                                    const int* __restrict__ rowptr,
                                                    const int* __restrict__ eidx,
                                                    const unsigned short* __restrict__ Wct,
                                                    const float* __restrict__ bias,
                                                    unsigned short* __restrict__ out, int M) {
    __shared__ __align__(16) unsigned short Msm[16384];   // mean tiles kt0-3
    __shared__ __align__(16) unsigned short Xsm[16384];   // xs tiles kt4-7
    const int t = threadIdx.x;
    const int w = t >> 6, l = t & 63;
    const int lrow = l & 15, slot = l >> 4;
    const int row0 = blockIdx.x * 64;

    // gather phase: mean -> Msm
    GATHER_MEAN(Msm, xs)
    __syncthreads();

    // stage all 4 xs tiles (kt4-7) up-front
    int a_row = row0 + w * 16 + lrow;
    if (a_row > M - 1) a_row = M - 1;
    const size_t a_base = (size_t)a_row * 256 + slot * 8;
#pragma unroll
    for (int kt = 0; kt < 4; ++kt) {
        const unsigned short* src = xs + a_base + kt * 64;
        gload16(src,      &Xsm[kt * 4096 + w * 1024]);
        gload16(src + 32, &Xsm[kt * 4096 + w * 1024 + 512]);
    }

    f32x4 acc[4][4];
#pragma unroll
    for (int n = 0; n < 4; ++n)
#pragma unroll
        for (int m = 0; m < 4; ++m)
#pragma unroll
            for (int j = 0; j < 4; ++j) acc[n][m][j] = 0.0f;

    bf16x8 af[4];
    // kt0-3: A from Msm (no staging, no barriers)
#pragma unroll
    for (int kt = 0; kt < 4; ++kt) {
        bf16x8 bfr[4][2];
#pragma unroll
        for (int m = 0; m < 4; ++m)
#pragma unroll
            for (int kk = 0; kk < 2; ++kk)
                bfr[m][kk] = *(const bf16x8*)(Wct + (size_t)kt * 16384
                                              + (size_t)(w * 4 + m) * 1024 + kk * 512 + l * 8);
#pragma unroll
        for (int kk = 0; kk < 2; ++kk) {
#pragma unroll
            for (int n = 0; n < 4; ++n)
                af[n] = *(const bf16x8*)(&Msm[kt * 4096 + n * 1024 + kk * 512 + l * 8]);
            __builtin_amdgcn_s_setprio(1);
#pragma unroll
            for (int n = 0; n < 4; ++n)
#pragma unroll
                for (int m = 0; m < 4; ++m)
                    acc[n][m] = __builtin_amdgcn_mfma_f32_16x16x32_bf16(bfr[m][kk], af[n], acc[n][m], 0, 0, 0);
            __builtin_amdgcn_s_setprio(0);
        }
    }
    // Xsm stages are long-retired (forced by kt0's B-load waits); one barrier for visibility
    asm volatile("s_waitcnt vmcnt(0)" ::: "memory");
    __builtin_amdgcn_s_barrier();
    // kt4-7: A from Xsm
#pragma unroll
    for (int kt = 4; kt < 8; ++kt) {
        bf16x8 bfr[4][2];
#pragma unroll
        for (int m = 0; m < 4; ++m)
#pragma unroll
            for (int kk = 0; kk < 2; ++kk)
                bfr[m][kk] = *(const bf16x8*)(Wct + (size_t)kt * 16384
                                              + (size_t)(w * 4 + m) * 1024 + kk * 512 + l * 8);
#pragma unroll
        for (int kk = 0; kk < 2; ++kk) {
#pragma unroll
            for (int n = 0; n < 4; ++n)
                af[n] = *(const bf16x8*)(&Xsm[(kt - 4) * 4096 + n * 1024 + kk * 512 + l * 8]);
            __builtin_amdgcn_s_setprio(1);
#pragma unroll
            for (int n = 0; n < 4; ++n)
#pragma unroll
                for (int m = 0; m < 4; ++m)
                    acc[n][m] = __builtin_amdgcn_mfma_f32_16x16x32_bf16(bfr[m][kk], af[n], acc[n][m], 0, 0, 0);
            __builtin_amdgcn_s_setprio(0);
        }
    }

#pragma unroll
    for (int n = 0; n < 4; ++n) {
        const int grow = row0 + n * 16 + lrow;
        if (grow >= M) continue;
#pragma unroll
        for (int m = 0; m < 4; ++m) {
            const int gcol = w * 64 + m * 16 + slot * 4;
            f32x4 bv = *(const f32x4*)(bias + gcol);
            us4 o;
            o.x = f2bf(fmaxf(acc[n][m][0] + bv.x, 0.f));
            o.y = f2bf(fmaxf(acc[n][m][1] + bv.y, 0.f));
            o.z = f2bf(fmaxf(acc[n][m][2] + bv.z, 0.f));
            o.w = f2bf(fmaxf(acc[n][m][3] + bv.w, 0.f));
            *(us4*)(out + (size_t)grow * 256 + gcol) = o;
        }
    }
}

// ---------------- FUSED gather + layer-2 GEMM + fc head ----------------
// Same structure; g tile goes to LDS (aliasing the dead mean tiles) then fc mini-GEMM.
__global__ __launch_bounds__(256, 2) void k_sage_g2fc(const unsigned short* __restrict__ xs,
                                                      const int* __restrict__ rowptr,
                                                      const int* __restrict__ eidx,
                                                      const unsigned short* __restrict__ Wct,
                                                      const float* __restrict__ bias,
                                                      const unsigned short* __restrict__ fcWbt,
                                                      const float* __restrict__ fcb,
                                                      float* __restrict__ out, int M) {
    __shared__ __align__(16) unsigned short pool[32768];  // [0..16383]=Msm / g-tile, [16384..]=Xsm
    unsigned short* Msm = pool;
    unsigned short* Xsm = pool + 16384;
    const int t = threadIdx.x;
    const int w = t >> 6, l = t & 63;
    const int lrow = l & 15, slot = l >> 4;
    const int row0 = blockIdx.x * 64;

    GATHER_MEAN(Msm, xs)
    __syncthreads();

    int a_row = row0 + w * 16 + lrow;
    if (a_row > M - 1) a_row = M - 1;
    const size_t a_base = (size_t)a_row * 256 + slot * 8;
#pragma unroll
    for (int kt = 0; kt < 4; ++kt) {
        const unsigned short* src = xs + a_base + kt * 64;
        gload16(src,      &Xsm[kt * 4096 + w * 1024]);
        gload16(src + 32, &Xsm[kt * 4096 + w * 1024 + 512]);
    }

    f32x4 acc[4][4];
#pragma unroll
    for (int n = 0; n < 4; ++n)
#pragma unroll
        for (int m = 0; m < 4; ++m)
#pragma unroll
            for (int j = 0; j < 4; ++j) acc[n][m][j] = 0.0f;

    bf16x8 af[4];
#pragma unroll
    for (int kt = 0; kt < 4; ++kt) {
        bf16x8 bfr[4][2];
#pragma unroll
        for (int m = 0; m < 4; ++m)
#pragma unroll
            for (int kk = 0; kk < 2; ++kk)
                bfr[m][kk] = *(const bf16x8*)(Wct + (size_t)kt * 16384
                                              + (size_t)(w * 4 + m) * 1024 + kk * 512 + l * 8);
#pragma unroll
        for (int kk = 0; kk < 2; ++kk) {
#pragma unroll
            for (int n = 0; n < 4; ++n)
                af[n] = *(const bf16x8*)(&Msm[kt * 4096 + n * 1024 + kk * 512 + l * 8]);
            __builtin_amdgcn_s_setprio(1);
#pragma unroll
            for (int n = 0; n < 4; ++n)
#pragma unroll
                for (int m = 0; m < 4; ++m)
                    acc[n][m] = __builtin_amdgcn_mfma_f32_16x16x32_bf16(bfr[m][kk], af[n], acc[n][m], 0, 0, 0);
            __builtin_amdgcn_s_setprio(0);
        }
    }
    asm volatile("s_waitcnt vmcnt(0)" ::: "memory");
    __builtin_amdgcn_s_barrier();
#pragma unroll
    for (int kt = 4; kt < 8; ++kt) {
        bf16x8 bfr[4][2];
#pragma unroll
        for (int m = 0; m < 4; ++m)
#pragma unroll
            for (int kk = 0; kk < 2; ++kk)
                bfr[m][kk] = *(const bf16x8*)(Wct + (size_t)kt * 16384
                                              + (size_t)(w * 4 + m) * 1024 + kk * 512 + l * 8);
#pragma unroll
        for (int kk = 0; kk < 2; ++kk) {
#pragma unroll
            for (int n = 0; n < 4; ++n)
                af[n] = *(const bf16x8*)(&Xsm[(kt - 4) * 4096 + n * 1024 + kk * 512 + l * 8]);
            __builtin_amdgcn_s_setprio(1);
#pragma unroll
            for (int n = 0; n < 4; ++n)
#pragma unroll
                for (int m = 0; m < 4; ++m)
                    acc[n][m] = __builtin_amdgcn_mfma_f32_16x16x32_bf16(bfr[m][kk], af[n], acc[n][m], 0, 0, 0);
            __builtin_amdgcn_s_setprio(0);
        }
    }

    // g = relu(acc + bias) -> bf16 -> pool (frag-major; wave w writes its own quarter)
    __syncthreads();   // all waves past Msm use
#pragma unroll
    for (int n = 0; n < 4; ++n) {
#pragma unroll
        for (int m = 0; m < 4; ++m) {
            const int gcol = w * 64 + m * 16 + slot * 4;
            f32x4 bv = *(const f32x4*)(bias + gcol);
            us4 o;
            o.x = f2bf(fmaxf(acc[n][m][0] + bv.x, 0.f));
            o.y = f2bf(fmaxf(acc[n][m][1] + bv.y, 0.f));
            o.z = f2bf(fmaxf(acc[n][m][2] + bv.z, 0.f));
            o.w = f2bf(fmaxf(acc[n][m][3] + bv.w, 0.f));
            int addr = w * 4096 + n * 1024 + (m >> 1) * 512
                     + ((((m & 1) * 2 + (slot >> 1)) * 16 + lrow) * 8) + (slot & 1) * 4;
            *(us4*)(&pool[addr]) = o;
        }
    }
    __syncthreads();

    // fc mini-GEMM: out[64x128] = g @ fcW^T + fcb
    f32x4 acc2[4][2];
#pragma unroll
    for (int n = 0; n < 4; ++n)
#pragma unroll
        for (int m = 0; m < 2; ++m)
#pragma unroll
            for (int j = 0; j < 4; ++j) acc2[n][m][j] = 0.0f;

#pragma unroll
    for (int kt2 = 0; kt2 < 4; ++kt2) {
        bf16x8 bw[2][2];
#pragma unroll
        for (int m = 0; m < 2; ++m)
#pragma unroll
            for (int kk = 0; kk < 2; ++kk)
                bw[m][kk] = *(const bf16x8*)(fcWbt + (size_t)kt2 * 8192
                                             + (size_t)(w * 2 + m) * 1024 + kk * 512 + l * 8);
#pragma unroll
        for (int kk = 0; kk < 2; ++kk) {
            bf16x8 ag[4];
#pragma unroll
            for (int n = 0; n < 4; ++n)
                ag[n] = *(const bf16x8*)(&pool[kt2 * 4096 + n * 1024 + kk * 512 + l * 8]);
#pragma unroll
            for (int n = 0; n < 4; ++n)
#pragma unroll
                for (int m = 0; m < 2; ++m)
                    acc2[n][m] = __builtin_amdgcn_mfma_f32_16x16x32_bf16(bw[m][kk], ag[n], acc2[n][m], 0, 0, 0);
        }
    }

#pragma unroll
    for (int n = 0; n < 4; ++n) {
        const int grow = row0 + n * 16 + lrow;
        if (grow >= M) continue;
#pragma unroll
        for (int m = 0; m < 2; ++m) {
            const int gcol = w * 32 + m * 16 + slot * 4;
            f32x4 bv = *(const f32x4*)(fcb + gcol);
            f32x4 o;
            o.x = acc2[n][m][0] + bv.x;
            o.y = acc2[n][m][1] + bv.y;
            o.z = acc2[n][m][2] + bv.z;
            o.w = acc2[n][m][3] + bv.w;
            *(f32x4*)(out + (size_t)grow * 128 + gcol) = o;
        }
    }
}

extern "C" void kernel_launch(void* const* d_in, const int* in_sizes, int n_in,
                              void* d_out, int out_size, void* d_ws, size_t ws_size,
                              hipStream_t stream) {
    const float* x_word = (const float*)d_in[0];
    const float* Wl  = (const float*)d_in[3];
    const float* bl  = (const float*)d_in[4];
    const float* Wr  = (const float*)d_in[5];
    const float* fcW = (const float*)d_in[6];
    const float* fcb = (const float*)d_in[7];
    const int* src = (const int*)d_in[8];
    const int* dst = (const int*)d_in[9];

    const int M = in_sizes[0] / 256;   // 200000
    const int E = in_sizes[8];         // 400000
    const int NB = (M + 1023) / 1024;

    char* ws = (char*)d_ws;
    size_t off = 0;
    auto alloc = [&](size_t bytes) {
        void* p = ws + off;
        off = (off + bytes + 255) & ~(size_t)255;
        return p;
    };
    int* cnt_i  = (int*)alloc((size_t)M * 4);
    int* rowptr = (int*)alloc((size_t)(M + 1) * 4);
    int* cursor = (int*)alloc((size_t)M * 4);
    int* eidx   = (int*)alloc((size_t)E * 4);
    int* bsum   = (int*)alloc((size_t)NB * 4);
    unsigned short* xb    = (unsigned short*)alloc((size_t)M * 256 * 2);
    unsigned short* h     = (unsigned short*)alloc((size_t)M * 256 * 2);
    unsigned short* Wc1   = (unsigned short*)alloc(131072 * 2);
    unsigned short* Wc2   = (unsigned short*)alloc(131072 * 2);
    unsigned short* fcWb  = (unsigned short*)alloc(32768 * 2);

    // CSR build
    k_zero<<<(M + 255) / 256, 256, 0, stream>>>(cnt_i, M);
    k_hist<<<(E + 255) / 256, 256, 0, stream>>>(dst, cnt_i, E);
    k_bsum<<<NB, 256, 0, stream>>>(cnt_i, bsum, M);
    k_scanb<<<1, 64, 0, stream>>>(bsum, NB, rowptr, M, E);
    k_rowptr<<<NB, 256, 0, stream>>>(cnt_i, bsum, rowptr, cursor, M);
    k_place<<<(E + 255) / 256, 256, 0, stream>>>(src, dst, cursor, eidx, E);

    // weights (tiled) + x -> bf16 (row-major)
    k_convw<<<1152, 256, 0, stream>>>(Wl, Wr, fcW, Wc1, Wc2, fcWb);
    k_convx<<<(M * 256 / 8 + 255) / 256, 256, 0, stream>>>(x_word, xb, M * 256 / 8);

    const int GB = (M + 63) / 64;

    // Layer 1 (fused gather + GEMM)
    k_sage_g1<<<GB, 256, 0, stream>>>(xb, rowptr, eidx, Wc1, bl, h, M);

    // Layer 2 + fc head (fused gather + GEMM + fc)
    k_sage_g2fc<<<GB, 256, 0, stream>>>(h, rowptr, eidx, Wc2, bl + 3 * 256, fcWb, fcb,
                                        (float*)d_out, M);
}